// Round 4
// baseline (337.306 us; speedup 1.0000x reference)
//
#include <hip/hip_runtime.h>
#include <hip/hip_bf16.h>

#define NROWS 16384
#define NCODES 8192
#define DIM 256
#define BM 64
#define BN 512
#define NTILES (NCODES / BN)              // 16
#define NCHUNKS (NTILES * 4)              // 64 chunks of k=64
#define CAP 32
#define MARGIN 3.0e-4f

typedef __attribute__((ext_vector_type(8))) short bf16x8;
typedef __attribute__((ext_vector_type(4))) float f32x4;

__device__ inline unsigned short f2bf(float f) {
    union { __hip_bfloat16 h; unsigned short u; } cv;
    cv.h = __float2bfloat16(f);
    return cv.u;
}
__device__ inline unsigned f2ord(float f) {
    unsigned u = __float_as_uint(f);
    return u ^ ((u >> 31) ? 0xFFFFFFFFu : 0x80000000u);
}
__device__ inline float ord2f(unsigned u) {
    unsigned v = (u & 0x80000000u) ? (u ^ 0x80000000u) : ~u;
    return __uint_as_float(v);
}

// EXACT numpy pairwise sum-of-squares for a 256-vector (validated round 2).
__device__ float pairwise256_sq(const float4* p) {
    float res[2];
    #pragma unroll
    for (int h = 0; h < 2; ++h) {
        float r[8];
        #pragma unroll
        for (int j = 0; j < 8; ++j) r[j] = 0.0f;
        #pragma unroll
        for (int g = 0; g < 16; ++g) {
            float4 v0 = p[h * 32 + g * 2];
            float4 v1 = p[h * 32 + g * 2 + 1];
            r[0] = __fadd_rn(r[0], __fmul_rn(v0.x, v0.x));
            r[1] = __fadd_rn(r[1], __fmul_rn(v0.y, v0.y));
            r[2] = __fadd_rn(r[2], __fmul_rn(v0.z, v0.z));
            r[3] = __fadd_rn(r[3], __fmul_rn(v0.w, v0.w));
            r[4] = __fadd_rn(r[4], __fmul_rn(v1.x, v1.x));
            r[5] = __fadd_rn(r[5], __fmul_rn(v1.y, v1.y));
            r[6] = __fadd_rn(r[6], __fmul_rn(v1.z, v1.z));
            r[7] = __fadd_rn(r[7], __fmul_rn(v1.w, v1.w));
        }
        res[h] = __fadd_rn(__fadd_rn(__fadd_rn(r[0], r[1]), __fadd_rn(r[2], r[3])),
                           __fadd_rn(__fadd_rn(r[4], r[5]), __fadd_rn(r[6], r[7])));
    }
    return __fadd_rn(res[0], res[1]);
}

// Fused: xsq for rows, wsq for codes (one launch).
__global__ __launch_bounds__(256) void sq_kernel(const float* __restrict__ x,
                                                 const float* __restrict__ w,
                                                 float* __restrict__ xsq,
                                                 float* __restrict__ wsq) {
    int gid = blockIdx.x * 256 + threadIdx.x;
    if (gid < NROWS)
        xsq[gid] = pairwise256_sq(reinterpret_cast<const float4*>(x + (size_t)gid * DIM));
    else
        wsq[gid - NROWS] =
            pairwise256_sq(reinterpret_cast<const float4*>(w + (size_t)(gid - NROWS) * DIM));
}

// Pre-swizzle W into MFMA B-fragment order (bf16), unchanged from round 3.
__global__ __launch_bounds__(256) void wfrag_kernel(const float* __restrict__ w,
                                                    unsigned short* __restrict__ whf) {
    int tid = blockIdx.x * 256 + threadIdx.x;      // 0 .. 262143
    int L = tid & 63;
    int rest = tid >> 6;
    int c16 = rest & 511;
    int k32 = rest >> 9;
    int code = c16 * 16 + (L & 15);
    int k = k32 * 32 + (L >> 4) * 8;
    const float4* p = reinterpret_cast<const float4*>(w + (size_t)code * DIM + k);
    float4 u0 = p[0], u1 = p[1];
    unsigned short tmp[8];
    tmp[0] = f2bf(u0.x); tmp[1] = f2bf(u0.y); tmp[2] = f2bf(u0.z); tmp[3] = f2bf(u0.w);
    tmp[4] = f2bf(u1.x); tmp[5] = f2bf(u1.y); tmp[6] = f2bf(u1.z); tmp[7] = f2bf(u1.w);
    *reinterpret_cast<uint4*>(whf + (size_t)tid * 8) = *reinterpret_cast<uint4*>(tmp);
}

// 256 threads (4 waves), 512-reg budget: afr(128)+acc(128) fit with NO spills.
__global__ __launch_bounds__(256, 1)
void vq_main(const float* __restrict__ x, const float* __restrict__ w,
             const unsigned short* __restrict__ whf,
             const float* __restrict__ wsq, const float* __restrict__ xsq,
             float* __restrict__ out_q, float* __restrict__ out_idx) {
    __shared__ unsigned short bbuf[2][BN * 64];   // 2 x 64 KB, fragment-linear
    __shared__ unsigned rowmin[BM];
    __shared__ int cnt[BM];
    __shared__ int cand[BM][CAP];
    __shared__ unsigned long long best64[BM];
    __shared__ int rowBest[BM];

    const int tid = threadIdx.x;
    const int lane = tid & 63;
    const int wv = tid >> 6;          // 0..3: wave = 128-code group
    const int lm = lane & 15;
    const int lq = lane >> 4;
    const int rowBase = blockIdx.x * BM;

    if (tid < BM) { rowmin[tid] = 0xFFFFFFFFu; cnt[tid] = 0; best64[tid] = ~0ull; }

    // A fragments in registers: lane holds x[rowBase+rg*16+lm][k32*32+lq*8+j]
    bf16x8 afr[4][8];
    #pragma unroll
    for (int rg = 0; rg < 4; ++rg) {
        const float* xr = x + (size_t)(rowBase + rg * 16 + lm) * DIM + lq * 8;
        #pragma unroll
        for (int k32 = 0; k32 < 8; ++k32) {
            float4 u0 = *reinterpret_cast<const float4*>(xr + k32 * 32);
            float4 u1 = *reinterpret_cast<const float4*>(xr + k32 * 32 + 4);
            bf16x8 a;
            a[0] = (short)f2bf(u0.x); a[1] = (short)f2bf(u0.y);
            a[2] = (short)f2bf(u0.z); a[3] = (short)f2bf(u0.w);
            a[4] = (short)f2bf(u1.x); a[5] = (short)f2bf(u1.y);
            a[6] = (short)f2bf(u1.z); a[7] = (short)f2bf(u1.w);
            afr[rg][k32] = a;
        }
    }

    // async stage of chunk g (k=64 slice of a 512-code tile) into bbuf[g&1]
    auto stage = [&](int g) {
        int t = g >> 2;
        unsigned short* lbuf = &bbuf[g & 1][0];
        #pragma unroll
        for (int i = 0; i < 16; ++i) {
            int f = wv * 16 + i;                      // fragment 0..63
            int k32 = (g & 3) * 2 + (f >> 5);
            int c16 = t * 32 + (f & 31);
            const unsigned short* gp = whf + (((size_t)(k32 * 512 + c16)) * 64 + lane) * 8;
            unsigned short* lp = lbuf + f * 512;      // wave-uniform base; HW adds lane*16B
            __builtin_amdgcn_global_load_lds(
                (const __attribute__((address_space(1))) unsigned int*)gp,
                (__attribute__((address_space(3))) unsigned int*)lp, 16, 0, 0);
        }
    };

    stage(0);

    for (int t = 0; t < NTILES; ++t) {
        f32x4 acc[4][8];
        #pragma unroll
        for (int rg = 0; rg < 4; ++rg)
            #pragma unroll
            for (int cf = 0; cf < 8; ++cf)
                acc[rg][cf] = (f32x4){0.f, 0.f, 0.f, 0.f};

        #pragma unroll
        for (int ch = 0; ch < 4; ++ch) {
            int g = t * 4 + ch;
            __syncthreads();                 // chunk g staged; buf (g+1)&1 free
            if (g + 1 < NCHUNKS) stage(g + 1);
            const unsigned short* buf = &bbuf[g & 1][0];
            #pragma unroll
            for (int kl = 0; kl < 2; ++kl) {
                int k32 = ch * 2 + kl;       // static index into afr
                #pragma unroll
                for (int cf = 0; cf < 8; ++cf) {
                    bf16x8 b = *reinterpret_cast<const bf16x8*>(
                        buf + (kl * 32 + wv * 8 + cf) * 512 + lane * 8);
                    #pragma unroll
                    for (int rg = 0; rg < 4; ++rg)
                        acc[rg][cf] = __builtin_amdgcn_mfma_f32_16x16x32_bf16(
                            afr[rg][k32], b, acc[rg][cf], 0, 0, 0);
                }
            }
        }

        // ---- approx score: s = wsq - 2*dot (xsq const per row) ----
        float wq[8];
        #pragma unroll
        for (int cf = 0; cf < 8; ++cf)
            wq[cf] = wsq[t * BN + wv * 128 + cf * 16 + lm];

        float mloc[16];
        #pragma unroll
        for (int rg = 0; rg < 4; ++rg) {
            #pragma unroll
            for (int r = 0; r < 4; ++r) {
                float m = __builtin_huge_valf();
                #pragma unroll
                for (int cf = 0; cf < 8; ++cf)
                    m = fminf(m, fmaf(-2.f, acc[rg][cf][r], wq[cf]));
                mloc[rg * 4 + r] = m;
                float rm = m;
                rm = fminf(rm, __shfl_xor(rm, 1, 64));
                rm = fminf(rm, __shfl_xor(rm, 2, 64));
                rm = fminf(rm, __shfl_xor(rm, 4, 64));
                rm = fminf(rm, __shfl_xor(rm, 8, 64));
                if (lm == 0)
                    atomicMin(&rowmin[rg * 16 + lq * 4 + r], f2ord(rm));
            }
        }
        // collect candidates vs a prefix min (no barrier needed: any stale
        // rowmin value is >= the final min, so collection stays a superset)
        #pragma unroll
        for (int rg = 0; rg < 4; ++rg) {
            #pragma unroll
            for (int r = 0; r < 4; ++r) {
                int row = rg * 16 + lq * 4 + r;
                float limit = ord2f(rowmin[row]) + MARGIN;
                if (mloc[rg * 4 + r] <= limit) {
                    #pragma unroll
                    for (int cf = 0; cf < 8; ++cf) {
                        float s = fmaf(-2.f, acc[rg][cf][r], wq[cf]);
                        if (s <= limit) {
                            int pos = atomicAdd(&cnt[row], 1);
                            if (pos < CAP)
                                cand[row][pos] = t * BN + wv * 128 + cf * 16 + lm;
                        }
                    }
                }
            }
        }
    }
    __syncthreads();

    // ---- exact rescore (bit-identical to round-2 validated formula) ----
    for (int slot = tid; slot < BM * CAP; slot += 256) {
        int row = slot / CAP, pos = slot % CAP;
        int n = cnt[row] < CAP ? cnt[row] : CAP;
        if (pos < n) {
            int c = cand[row][pos];
            const float* xr = x + (size_t)(rowBase + row) * DIM;
            const float* wr = w + (size_t)c * DIM;
            float d = 0.f;
            for (int k = 0; k < DIM; k += 4) {
                float4 a = *reinterpret_cast<const float4*>(xr + k);
                float4 b = *reinterpret_cast<const float4*>(wr + k);
                d = fmaf(a.x, b.x, d);
                d = fmaf(a.y, b.y, d);
                d = fmaf(a.z, b.z, d);
                d = fmaf(a.w, b.w, d);
            }
            float t1 = __fadd_rn(xsq[rowBase + row], wsq[c]);
            float s = __fsub_rn(t1, __fadd_rn(d, d));
            unsigned long long key =
                ((unsigned long long)__float_as_uint(s) << 32) | (unsigned)c;
            atomicMin(&best64[row], key);   // s>0 (xsq~256): bit order = float order
        }
    }
    __syncthreads();
    if (tid < BM) {
        int idx = (int)(best64[tid] & 0xFFFFFFFFu);
        rowBest[tid] = idx;
        out_idx[rowBase + tid] = (float)idx;
    }
    __syncthreads();

    // gather winning codewords, coalesced float4
    #pragma unroll
    for (int it = 0; it < 16; ++it) {
        int r = it * 4 + wv;
        int code = rowBest[r];
        float4 v = reinterpret_cast<const float4*>(w + (size_t)code * DIM)[lane];
        reinterpret_cast<float4*>(out_q + (size_t)(rowBase + r) * DIM)[lane] = v;
    }
}

extern "C" void kernel_launch(void* const* d_in, const int* in_sizes, int n_in,
                              void* d_out, int out_size, void* d_ws, size_t ws_size,
                              hipStream_t stream) {
    const float* x = (const float*)d_in[0];   // (16384, 256) fp32
    const float* w = (const float*)d_in[1];   // (8192, 256) fp32
    float* out_q = (float*)d_out;
    float* out_idx = (float*)d_out + (size_t)NROWS * DIM;

    unsigned short* whf = (unsigned short*)d_ws;                    // 4 MB bf16 frags
    float* wsq = (float*)((char*)d_ws + (size_t)NCODES * DIM * 2);  // 32 KB
    float* xsq = wsq + NCODES;                                      // 64 KB

    wfrag_kernel<<<(NCODES * DIM / 8) / 256, 256, 0, stream>>>(w, whf);
    sq_kernel<<<(NROWS + NCODES) / 256, 256, 0, stream>>>(x, w, xsq, wsq);
    vq_main<<<NROWS / BM, 256, 0, stream>>>(x, w, whf, wsq, xsq, out_q, out_idx);
}

// Round 5
// 264.113 us; speedup vs baseline: 1.2771x; 1.2771x over previous
//
#include <hip/hip_runtime.h>
#include <hip/hip_bf16.h>

#define NROWS 16384
#define NCODES 8192
#define DIM 256
#define BM 128                     // rows per block
#define CPB 4096                   // codes per block (2-way split)
#define CAP 24
#define MARGIN 3.0e-4f

typedef __attribute__((ext_vector_type(8))) short bf16x8;
typedef __attribute__((ext_vector_type(4))) float f32x4;

__device__ inline unsigned short f2bf(float f) {
    union { __hip_bfloat16 h; unsigned short u; } cv;
    cv.h = __float2bfloat16(f);
    return cv.u;
}
__device__ inline unsigned f2ord(float f) {
    unsigned u = __float_as_uint(f);
    return u ^ ((u >> 31) ? 0xFFFFFFFFu : 0x80000000u);
}
__device__ inline float ord2f(unsigned u) {
    unsigned v = (u & 0x80000000u) ? (u ^ 0x80000000u) : ~u;
    return __uint_as_float(v);
}

// EXACT numpy pairwise sum-of-squares for a 256-vector (validated round 2).
__device__ float pairwise256_sq(const float4* p) {
    float res[2];
    #pragma unroll
    for (int h = 0; h < 2; ++h) {
        float r[8];
        #pragma unroll
        for (int j = 0; j < 8; ++j) r[j] = 0.0f;
        #pragma unroll
        for (int g = 0; g < 16; ++g) {
            float4 v0 = p[h * 32 + g * 2];
            float4 v1 = p[h * 32 + g * 2 + 1];
            r[0] = __fadd_rn(r[0], __fmul_rn(v0.x, v0.x));
            r[1] = __fadd_rn(r[1], __fmul_rn(v0.y, v0.y));
            r[2] = __fadd_rn(r[2], __fmul_rn(v0.z, v0.z));
            r[3] = __fadd_rn(r[3], __fmul_rn(v0.w, v0.w));
            r[4] = __fadd_rn(r[4], __fmul_rn(v1.x, v1.x));
            r[5] = __fadd_rn(r[5], __fmul_rn(v1.y, v1.y));
            r[6] = __fadd_rn(r[6], __fmul_rn(v1.z, v1.z));
            r[7] = __fadd_rn(r[7], __fmul_rn(v1.w, v1.w));
        }
        res[h] = __fadd_rn(__fadd_rn(__fadd_rn(r[0], r[1]), __fadd_rn(r[2], r[3])),
                           __fadd_rn(__fadd_rn(r[4], r[5]), __fadd_rn(r[6], r[7])));
    }
    return __fadd_rn(res[0], res[1]);
}

__global__ __launch_bounds__(256) void sq_kernel(const float* __restrict__ x,
                                                 const float* __restrict__ w,
                                                 float* __restrict__ xsq,
                                                 float* __restrict__ wsq) {
    int gid = blockIdx.x * 256 + threadIdx.x;
    if (gid < NROWS)
        xsq[gid] = pairwise256_sq(reinterpret_cast<const float4*>(x + (size_t)gid * DIM));
    else
        wsq[gid - NROWS] =
            pairwise256_sq(reinterpret_cast<const float4*>(w + (size_t)(gid - NROWS) * DIM));
}

// Pre-swizzle W into MFMA B-fragment order (bf16).
// flat unit tid = (k32*512 + c16)*64 + L holds 8 bf16 =
//   W[c16*16 + (L&15)][k32*32 + (L>>4)*8 + j]
__global__ __launch_bounds__(256) void wfrag_kernel(const float* __restrict__ w,
                                                    unsigned short* __restrict__ whf) {
    int tid = blockIdx.x * 256 + threadIdx.x;      // 0 .. 262143
    int L = tid & 63;
    int rest = tid >> 6;
    int c16 = rest & 511;
    int k32 = rest >> 9;
    int code = c16 * 16 + (L & 15);
    int k = k32 * 32 + (L >> 4) * 8;
    const float4* p = reinterpret_cast<const float4*>(w + (size_t)code * DIM + k);
    float4 u0 = p[0], u1 = p[1];
    unsigned short tmp[8];
    tmp[0] = f2bf(u0.x); tmp[1] = f2bf(u0.y); tmp[2] = f2bf(u0.z); tmp[3] = f2bf(u0.w);
    tmp[4] = f2bf(u1.x); tmp[5] = f2bf(u1.y); tmp[6] = f2bf(u1.z); tmp[7] = f2bf(u1.w);
    *reinterpret_cast<uint4*>(whf + (size_t)tid * 8) = *reinterpret_cast<uint4*>(tmp);
}

// Main: 512 thr (8 waves), A-tile in LDS, B global->reg, barrier-free K-loop.
__global__ __launch_bounds__(512, 2)
void vq_main(const float* __restrict__ x, const float* __restrict__ w,
             const unsigned short* __restrict__ whf,
             const float* __restrict__ wsq, const float* __restrict__ xsq,
             unsigned long long* __restrict__ best64g) {
    __shared__ unsigned short afrag[8 * 8 * 64 * 8];   // rg,k32,lane -> 16B frag; 64 KB
    __shared__ unsigned rowmin[BM];
    __shared__ int cnt[BM];
    __shared__ int cand[BM][CAP];

    const int tid = threadIdx.x;
    const int lane = tid & 63;
    const int wv = tid >> 6;          // 0..7
    const int lm = lane & 15;
    const int lq = lane >> 4;

    // block -> (split, rowGroup); same-split blocks cluster per XCD (L2 locality)
    const int blk = blockIdx.x;
    const int xcd = blk & 7;
    const int split = xcd & 1;
    const int rowGroup = (xcd >> 1) * 32 + (blk >> 3);   // bijective 0..127 per split
    const int rowBase = rowGroup * BM;
    const int codeBase = split * CPB;

    if (tid < BM) { rowmin[tid] = 0xFFFFFFFFu; cnt[tid] = 0; }

    // ---- stage A tile once (bf16, fragment order); wave wv handles rg=wv ----
    {
        const int rg = wv;
        const float* xr = x + (size_t)(rowBase + rg * 16 + lm) * DIM + lq * 8;
        #pragma unroll
        for (int k32 = 0; k32 < 8; ++k32) {
            float4 u0 = *reinterpret_cast<const float4*>(xr + k32 * 32);
            float4 u1 = *reinterpret_cast<const float4*>(xr + k32 * 32 + 4);
            unsigned short t8[8];
            t8[0] = f2bf(u0.x); t8[1] = f2bf(u0.y); t8[2] = f2bf(u0.z); t8[3] = f2bf(u0.w);
            t8[4] = f2bf(u1.x); t8[5] = f2bf(u1.y); t8[6] = f2bf(u1.z); t8[7] = f2bf(u1.w);
            *reinterpret_cast<uint4*>(afrag + ((rg * 8 + k32) * 64 + lane) * 8) =
                *reinterpret_cast<uint4*>(t8);
        }
    }
    __syncthreads();   // the ONLY barrier before the final reduction

    const int waveCode16 = (codeBase + wv * 512) >> 4;   // base c16 for this wave

    for (int p = 0; p < 8; ++p) {                        // 8 passes x 64 codes
        const int pbase16 = waveCode16 + p * 4;
        f32x4 acc[8][4];
        #pragma unroll
        for (int rg = 0; rg < 8; ++rg)
            #pragma unroll
            for (int cf = 0; cf < 4; ++cf)
                acc[rg][cf] = (f32x4){0.f, 0.f, 0.f, 0.f};

        bf16x8 bb[2][4];
        #pragma unroll
        for (int cf = 0; cf < 4; ++cf)
            bb[0][cf] = *reinterpret_cast<const bf16x8*>(
                whf + (((size_t)(pbase16 + cf)) * 64 + lane) * 8);

        #pragma unroll
        for (int k32 = 0; k32 < 8; ++k32) {
            const int cur = k32 & 1;
            if (k32 < 7) {
                #pragma unroll
                for (int cf = 0; cf < 4; ++cf)
                    bb[cur ^ 1][cf] = *reinterpret_cast<const bf16x8*>(
                        whf + (((size_t)((k32 + 1) * 512 + pbase16 + cf)) * 64 + lane) * 8);
            }
            bf16x8 a[8];
            #pragma unroll
            for (int rg = 0; rg < 8; ++rg)
                a[rg] = *reinterpret_cast<const bf16x8*>(
                    afrag + ((rg * 8 + k32) * 64 + lane) * 8);
            #pragma unroll
            for (int cf = 0; cf < 4; ++cf)
                #pragma unroll
                for (int rg = 0; rg < 8; ++rg)
                    acc[rg][cf] = __builtin_amdgcn_mfma_f32_16x16x32_bf16(
                        a[rg], bb[cur][cf], acc[rg][cf], 0, 0, 0);
        }

        // ---- approx score: s = wsq - 2*dot ----
        float wq[4];
        #pragma unroll
        for (int cf = 0; cf < 4; ++cf)
            wq[cf] = wsq[(pbase16 + cf) * 16 + lm];

        float mloc[32];
        #pragma unroll
        for (int rg = 0; rg < 8; ++rg) {
            #pragma unroll
            for (int r = 0; r < 4; ++r) {
                float m = __builtin_huge_valf();
                #pragma unroll
                for (int cf = 0; cf < 4; ++cf)
                    m = fminf(m, fmaf(-2.f, acc[rg][cf][r], wq[cf]));
                mloc[rg * 4 + r] = m;
                float rm = m;
                rm = fminf(rm, __shfl_xor(rm, 1, 64));
                rm = fminf(rm, __shfl_xor(rm, 2, 64));
                rm = fminf(rm, __shfl_xor(rm, 4, 64));
                rm = fminf(rm, __shfl_xor(rm, 8, 64));
                if (lm == 0)
                    atomicMin(&rowmin[rg * 16 + lq * 4 + r], f2ord(rm));
            }
        }
        // collect candidates vs prefix min (stale rowmin => superset, safe)
        #pragma unroll
        for (int rg = 0; rg < 8; ++rg) {
            #pragma unroll
            for (int r = 0; r < 4; ++r) {
                const int row = rg * 16 + lq * 4 + r;
                float limit = ord2f(rowmin[row]) + MARGIN;
                if (mloc[rg * 4 + r] <= limit) {
                    #pragma unroll
                    for (int cf = 0; cf < 4; ++cf) {
                        float s = fmaf(-2.f, acc[rg][cf][r], wq[cf]);
                        if (s <= limit) {
                            int pos = atomicAdd(&cnt[row], 1);
                            if (pos < CAP)
                                cand[row][pos] = (pbase16 + cf) * 16 + lm;
                        }
                    }
                }
            }
        }
    }
    __syncthreads();

    // ---- exact rescore (bit-identical to round-2 validated formula) ----
    for (int slot = tid; slot < BM * CAP; slot += 512) {
        int row = slot / CAP, pos = slot - (slot / CAP) * CAP;
        int n = cnt[row] < CAP ? cnt[row] : CAP;
        if (pos < n) {
            int c = cand[row][pos];
            const float* xr = x + (size_t)(rowBase + row) * DIM;
            const float* wr = w + (size_t)c * DIM;
            float d = 0.f;
            for (int k = 0; k < DIM; k += 4) {
                float4 a = *reinterpret_cast<const float4*>(xr + k);
                float4 b = *reinterpret_cast<const float4*>(wr + k);
                d = fmaf(a.x, b.x, d);
                d = fmaf(a.y, b.y, d);
                d = fmaf(a.z, b.z, d);
                d = fmaf(a.w, b.w, d);
            }
            float t1 = __fadd_rn(xsq[rowBase + row], wsq[c]);
            float s = __fsub_rn(t1, __fadd_rn(d, d));
            unsigned long long key =
                ((unsigned long long)__float_as_uint(s) << 32) | (unsigned)c;
            atomicMin(best64g + rowBase + row, key);   // s>0: bit order = float order
        }
    }
}

// Final: read per-row best key, write index + gather codeword.
__global__ __launch_bounds__(256)
void out_kernel(const float* __restrict__ w,
                const unsigned long long* __restrict__ best64g,
                float* __restrict__ out_q, float* __restrict__ out_idx) {
    int r = blockIdx.x * 4 + (threadIdx.x >> 6);
    int lane = threadIdx.x & 63;
    unsigned long long key = best64g[r];
    int idx = (int)(key & 0xFFFFFFFFu);
    float4 v = reinterpret_cast<const float4*>(w + (size_t)idx * DIM)[lane];
    reinterpret_cast<float4*>(out_q + (size_t)r * DIM)[lane] = v;
    if (lane == 0) out_idx[r] = (float)idx;
}

extern "C" void kernel_launch(void* const* d_in, const int* in_sizes, int n_in,
                              void* d_out, int out_size, void* d_ws, size_t ws_size,
                              hipStream_t stream) {
    const float* x = (const float*)d_in[0];   // (16384, 256) fp32
    const float* w = (const float*)d_in[1];   // (8192, 256) fp32
    float* out_q = (float*)d_out;
    float* out_idx = (float*)d_out + (size_t)NROWS * DIM;

    unsigned short* whf = (unsigned short*)d_ws;                      // 4 MB
    float* wsq = (float*)((char*)d_ws + (size_t)NCODES * DIM * 2);    // 32 KB
    float* xsq = wsq + NCODES;                                        // 64 KB
    unsigned long long* best64g = (unsigned long long*)(xsq + NROWS); // 128 KB

    wfrag_kernel<<<(NCODES * DIM / 8) / 256, 256, 0, stream>>>(w, whf);
    sq_kernel<<<(NROWS + NCODES) / 256, 256, 0, stream>>>(x, w, xsq, wsq);
    hipMemsetAsync(best64g, 0xFF, (size_t)NROWS * 8, stream);
    vq_main<<<256, 512, 0, stream>>>(x, w, whf, wsq, xsq, best64g);
    out_kernel<<<NROWS / 4, 256, 0, stream>>>(w, best64g, out_q, out_idx);
}